// Round 15
// baseline (1290.412 us; speedup 1.0000x reference)
//
#include <hip/hip_runtime.h>

#define GEMM_GRID 768   // 3 blocks/CU. R8's 768-regression was confounded by
                        // per-block f2bf W-staging; W is now pre-converted (R9),
                        // so re-test occupancy cleanly. LDS 52KB*3 = 156 <= 160K.
#define GNUM 4096   // num graphs (fixed in reference)

typedef __attribute__((ext_vector_type(8))) short short8_t;
typedef __attribute__((ext_vector_type(4))) float f32x4;
typedef __attribute__((ext_vector_type(2))) float v2f;

__device__ __forceinline__ float bf2f(unsigned short u) {
    union { unsigned int i; float f; } v; v.i = ((unsigned int)u) << 16; return v.f;
}
__device__ __forceinline__ unsigned short f2bf(float f) {
    union { float f; unsigned int i; } v; v.f = f;
    unsigned int b = v.i + 0x7FFFu + ((v.i >> 16) & 1u);
    return (unsigned short)(b >> 16);
}
__device__ __forceinline__ float lrelu(float v) { return v > 0.f ? v : 0.01f * v; }

// ================================================================ CSR build
__global__ __launch_bounds__(256) void hist_kernel(
    const int* __restrict__ dstv, int* __restrict__ cnt, int E)
{
    int i = blockIdx.x * 256 + threadIdx.x;
    if (i < E) atomicAdd(&cnt[dstv[i] + 1], 1);
}

__global__ __launch_bounds__(256) void scan_block_kernel(
    int* __restrict__ data, int* __restrict__ bsum, int n)
{
    __shared__ int s[256];
    int tid = threadIdx.x;
    int base = blockIdx.x * 1024 + tid * 4;
    int v[4]; int run = 0;
    #pragma unroll
    for (int i = 0; i < 4; i++) {
        int x = (base + i < n) ? data[base + i] : 0;
        run += x; v[i] = run;
    }
    s[tid] = run; __syncthreads();
    for (int off = 1; off < 256; off <<= 1) {
        int t = (tid >= off) ? s[tid - off] : 0;
        __syncthreads();
        s[tid] += t;
        __syncthreads();
    }
    int excl = s[tid] - run;
    #pragma unroll
    for (int i = 0; i < 4; i++)
        if (base + i < n) data[base + i] = v[i] + excl;
    if (tid == 255) bsum[blockIdx.x] = s[255];
}

__global__ __launch_bounds__(128) void scan_carry_kernel(int* __restrict__ bsum, int nb)
{
    __shared__ int s[128];
    int tid = threadIdx.x;
    int orig = (tid < nb) ? bsum[tid] : 0;
    s[tid] = orig; __syncthreads();
    for (int off = 1; off < 128; off <<= 1) {
        int t = (tid >= off) ? s[tid - off] : 0;
        __syncthreads();
        s[tid] += t;
        __syncthreads();
    }
    if (tid < nb) bsum[tid] = s[tid] - orig;
}

__global__ __launch_bounds__(256) void scan_add_kernel(
    int* __restrict__ data, const int* __restrict__ bsum,
    int* __restrict__ cursor, int n, int N)
{
    int i = blockIdx.x * 256 + threadIdx.x;
    if (i < n) {
        int v = data[i] + bsum[i >> 10];
        data[i] = v;
        if (i < N) cursor[i] = v;
    }
}

// non-RO fallback: plain scatter producing perm
__global__ __launch_bounds__(256) void scatter_kernel(
    const int* __restrict__ dstv, int* __restrict__ cursor,
    int* __restrict__ perm, int E)
{
    int i = blockIdx.x * 256 + threadIdx.x;
    if (i < E) {
        int p = atomicAdd(&cursor[dstv[i]], 1);
        perm[p] = i;
    }
}

// RO path: fused scatter+reorder. Coalesced 64B ea read, scattered 64B write.
// PLAIN loads/stores: NT stores measured 3x write amplification (R12, 347us);
// NT loads measured +38us/dispatch on gather128 with FETCH unchanged (R13).
__global__ __launch_bounds__(256) void scatter_reorder_kernel(
    const int* __restrict__ dstv, const int* __restrict__ srcv,
    const float* __restrict__ ea, int* __restrict__ cursor,
    float* __restrict__ eap, int* __restrict__ srcp, int E)
{
    int i = blockIdx.x * 256 + threadIdx.x;
    if (i >= E) return;
    int p = atomicAdd(&cursor[dstv[i]], 1);
    srcp[p] = srcv[i];
    const float4* s = reinterpret_cast<const float4*>(ea) + (size_t)i * 4;
    float4* d = reinterpret_cast<float4*>(eap) + (size_t)p * 4;
    float4 v0 = s[0], v1 = s[1], v2 = s[2], v3 = s[3];
    d[0] = v0; d[1] = v1; d[2] = v2; d[3] = v3;
}

// ================================================================ W pre-convert (bf16, transposed)
// Output layout per matrix: WT[nn*K + k] = f2bf(W[k*128 + nn]).
// Segments: w10 (K=32, 4096) then w20,w11,w21,w12,w22 (K=128, 16384 each).
__global__ __launch_bounds__(256) void wconv_kernel(
    const float* __restrict__ w10, const float* __restrict__ w20,
    const float* __restrict__ w11, const float* __restrict__ w21,
    const float* __restrict__ w12, const float* __restrict__ w22,
    unsigned short* __restrict__ wt)
{
    int idx = blockIdx.x * 256 + threadIdx.x;
    if (idx < 4096) {
        int nn = idx >> 5, k = idx & 31;
        wt[idx] = f2bf(w10[k * 128 + nn]);
        return;
    }
    int r = idx - 4096;
    int seg = r >> 14;
    if (seg >= 5) return;
    int o = r & 16383;
    int nn = o >> 7, k = o & 127;
    const float* w = (seg == 0) ? w20 : (seg == 1) ? w11 : (seg == 2) ? w21
                   : (seg == 3) ? w12 : w22;
    wt[4096 + seg * 16384 + o] = f2bf(w[k * 128 + nn]);
    (void)nn;
}

// ================================================================ gather, layer 0 (C=32, raw x0)
// 32-edge chunk, one latency exposure per chunk (Round-3 winner).
template<bool RO>
__global__ __launch_bounds__(256) void gather_kernel32(
    const float* __restrict__ ea, const int* __restrict__ srcv,
    const int* __restrict__ perm, const int* __restrict__ off,
    const float* __restrict__ ew, const float* __restrict__ ebias,
    const float* __restrict__ epsp, const float* __restrict__ x,
    unsigned short* __restrict__ aggh, unsigned short* __restrict__ aggl, int N)
{
    __shared__ float ebuf[4][32 * 16];     // per-wave 2 KB ea staging
    const int tid = threadIdx.x;
    const int wv = tid >> 6;
    const int lane = tid & 63;
    int n = __builtin_amdgcn_readfirstlane((int)((blockIdx.x * 256 + tid) >> 6));
    if (n >= N) return;
    const int h = lane >> 5;               // half-wave: 0 -> edges 0-15, 1 -> 16-31
    const int c = lane & 31;               // channel
    float ewr[16];
    #pragma unroll
    for (int k = 0; k < 16; k++) ewr[k] = ew[k * 32 + c];
    const float ebr = ebias[c];
    const float xself = x[(size_t)n * 32 + c];
    float acc = 0.f;
    const int p0 = off[n], end = off[n + 1];
    float* eb_ = ebuf[wv];
    const float4* eaq = reinterpret_cast<const float4*>(ea);

    for (int p = p0; p < end; p += 32) {
        // ---- phase 1: index loads (broadcast per half) + cooperative ea loads
        int sv[16];
        #pragma unroll
        for (int j = 0; j < 16; j++) {
            int pj = min(p + h * 16 + j, end - 1);
            int e = RO ? pj : perm[pj];
            sv[j] = srcv[e];
        }
        int rowA = min(p + (lane >> 2), end - 1);
        int rowB = min(p + 16 + (lane >> 2), end - 1);
        int erA = RO ? rowA : perm[rowA];
        int erB = RO ? rowB : perm[rowB];
        float4 eaA = eaq[(size_t)erA * 4 + (lane & 3)];
        float4 eaB = eaq[(size_t)erB * 4 + (lane & 3)];
        __builtin_amdgcn_sched_barrier(0);
        // ---- phase 2: batched x row loads (16 independent, coalesced)
        float xv[16];
        #pragma unroll
        for (int j = 0; j < 16; j++)
            xv[j] = x[(size_t)sv[j] * 32 + c];
        __builtin_amdgcn_sched_barrier(0);
        // ---- phase 3: stage ea to LDS (same-wave: fence, no barrier)
        __threadfence_block();
        *reinterpret_cast<float4*>(&eb_[(lane >> 2) * 16 + (lane & 3) * 4]) = eaA;
        *reinterpret_cast<float4*>(&eb_[(16 + (lane >> 2)) * 16 + (lane & 3) * 4]) = eaB;
        __threadfence_block();
        // ---- phase 4: compute 16 edges (this half's rows)
        #pragma unroll
        for (int j = 0; j < 16; j++) {
            int row = h * 16 + j;
            const float4* er4 = reinterpret_cast<const float4*>(&eb_[row * 16]);
            float4 e0 = er4[0], e1 = er4[1], e2 = er4[2], e3 = er4[3];
            float u = ebr;
            u = fmaf(e0.x, ewr[0], u);  u = fmaf(e0.y, ewr[1], u);
            u = fmaf(e0.z, ewr[2], u);  u = fmaf(e0.w, ewr[3], u);
            u = fmaf(e1.x, ewr[4], u);  u = fmaf(e1.y, ewr[5], u);
            u = fmaf(e1.z, ewr[6], u);  u = fmaf(e1.w, ewr[7], u);
            u = fmaf(e2.x, ewr[8], u);  u = fmaf(e2.y, ewr[9], u);
            u = fmaf(e2.z, ewr[10], u); u = fmaf(e2.w, ewr[11], u);
            u = fmaf(e3.x, ewr[12], u); u = fmaf(e3.y, ewr[13], u);
            u = fmaf(e3.z, ewr[14], u); u = fmaf(e3.w, ewr[15], u);
            bool valid = (p + row) < end;
            acc += valid ? fmaxf(xv[j] + u, 0.f) : 0.f;
        }
    }
    acc += __shfl_xor(acc, 32);
    if (lane < 32) {
        float s = 1.f + epsp[0];
        float f = fmaf(xself, s, acc);
        unsigned int b = __float_as_uint(f);
        unsigned short hi = (unsigned short)(b >> 16);
        float lo = f - __uint_as_float(b & 0xffff0000u);
        aggh[(size_t)n * 32 + c] = hi;
        aggl[(size_t)n * 32 + c] = f2bf(lo);
    }
}

// ================================================================ gather, layers 1/2 (C=128)
// Known-good configuration: 4 edges/iter, batched loads, wave-uniform edge
// indices -> ea rows + sv live in SGPRs (s_load path), VGPR 32 / SGPR 96.
template<bool RO>
__global__ __launch_bounds__(256) void gather_kernel128_bn(
    const float* __restrict__ ea, const int* __restrict__ srcv,
    const int* __restrict__ perm, const int* __restrict__ off,
    const float* __restrict__ ew, const float* __restrict__ ebias,
    const float* __restrict__ epsp, const float* __restrict__ U,
    const float* __restrict__ stats, const float* __restrict__ g,
    const float* __restrict__ be, float invN,
    unsigned short* __restrict__ aggh, unsigned short* __restrict__ aggl, int N)
{
    int lane = threadIdx.x & 63;
    int n = __builtin_amdgcn_readfirstlane((int)((blockIdx.x * 256 + threadIdx.x) >> 6));
    if (n >= N) return;
    const int c0 = lane * 2;
    v2f scv, shv;
    {
        float m0 = stats[c0] * invN;
        float v0 = fmaxf(stats[128 + c0] * invN - m0 * m0, 0.f);
        scv.x = g[c0] * rsqrtf(v0 + 1e-5f);
        shv.x = be[c0] - m0 * scv.x;
        float m1 = stats[c0 + 1] * invN;
        float v1 = fmaxf(stats[128 + c0 + 1] * invN - m1 * m1, 0.f);
        scv.y = g[c0 + 1] * rsqrtf(v1 + 1e-5f);
        shv.y = be[c0 + 1] - m1 * scv.y;
    }
    v2f ewv[16];
    #pragma unroll
    for (int k = 0; k < 16; k++)
        ewv[k] = *reinterpret_cast<const v2f*>(&ew[k * 128 + c0]);
    const v2f ebv = *reinterpret_cast<const v2f*>(&ebias[c0]);
    const v2f xn = *reinterpret_cast<const v2f*>(&U[(size_t)n * 128 + c0]);  // hoisted
    v2f acc = {0.f, 0.f};
    const int p0 = off[n];
    const int end = off[n + 1];
    for (int p = p0; p < end; p += 4) {
        int ee[4]; bool vv[4];
        #pragma unroll
        for (int j = 0; j < 4; j++) {
            int pj = p + j;
            vv[j] = pj < end;
            int ij = vv[j] ? pj : p;
            ee[j] = RO ? ij : perm[ij];
        }
        int ss[4];
        #pragma unroll
        for (int j = 0; j < 4; j++) ss[j] = srcv[ee[j]];
        float4 at[4][4];
        #pragma unroll
        for (int j = 0; j < 4; j++) {
            const float4* ap = reinterpret_cast<const float4*>(ea + (size_t)ee[j] * 16);
            #pragma unroll
            for (int q = 0; q < 4; q++) at[j][q] = ap[q];
        }
        v2f xv[4];
        #pragma unroll
        for (int j = 0; j < 4; j++)
            xv[j] = *reinterpret_cast<const v2f*>(&U[(size_t)ss[j] * 128 + c0]);
        __builtin_amdgcn_sched_barrier(0);   // pin: all loads issue before compute
        #pragma unroll
        for (int j = 0; j < 4; j++) {
            float av[16];
            #pragma unroll
            for (int q = 0; q < 4; q++) {
                av[4*q] = at[j][q].x; av[4*q+1] = at[j][q].y;
                av[4*q+2] = at[j][q].z; av[4*q+3] = at[j][q].w;
            }
            v2f xb = xv[j] * scv + shv;
            xb.x = lrelu(xb.x); xb.y = lrelu(xb.y);
            v2f u = ebv;
            #pragma unroll
            for (int k = 0; k < 16; k++) u = ewv[k] * av[k] + u;
            v2f m = xb + u;
            m.x = fmaxf(m.x, 0.f); m.y = fmaxf(m.y, 0.f);
            acc.x += vv[j] ? m.x : 0.f;
            acc.y += vv[j] ? m.y : 0.f;
        }
    }
    v2f xnb = xn * scv + shv;
    xnb.x = lrelu(xnb.x); xnb.y = lrelu(xnb.y);
    float s = 1.f + epsp[0];
    v2f o = xnb * s + acc;
    // split-pack: hi = trunc-top16, lo = residual (RNE)
    unsigned int b0 = __float_as_uint(o.x);
    unsigned int b1 = __float_as_uint(o.y);
    unsigned int hp = __builtin_amdgcn_perm(b1, b0, 0x07060302u);
    float l0 = o.x - __uint_as_float(b0 & 0xffff0000u);
    float l1 = o.y - __uint_as_float(b1 & 0xffff0000u);
    unsigned int lp = (unsigned int)f2bf(l0) | ((unsigned int)f2bf(l1) << 16);
    *reinterpret_cast<unsigned int*>(&aggh[(size_t)n * 128 + c0]) = hp;
    *reinterpret_cast<unsigned int*>(&aggl[(size_t)n * 128 + c0]) = lp;
}

// ================================================================ MFMA GEMM, copy-staged (pre-split A)
// out[N,128](fp32) = A @ W + bias; A given as bf16 hi/lo planes.
// W given pre-converted/pre-transposed bf16 (Wpre[nn*K+k]) -> staging is
// a pure uint4 copy (per-block f2bf eliminated; R8 measured setup cost).
template<int K>
__global__ __launch_bounds__(256, 3) void gemm_copy_mfma_kernel(
    const unsigned short* __restrict__ Ah, const unsigned short* __restrict__ Al,
    const unsigned short* __restrict__ Wpre, const float* __restrict__ bias,
    float* __restrict__ out, float* __restrict__ stats_out, int N, int ntiles)
{
    constexpr int PA = K + 8;
    __shared__ unsigned short As_hi[32 * PA];
    __shared__ unsigned short As_lo[32 * PA];
    __shared__ unsigned short Wt[128 * PA];
    const int tid = threadIdx.x;
    const int w = tid >> 6;
    const int lane = tid & 63;
    const int quad = lane >> 4;
    const int l16 = lane & 15;
    const int rbase = (w & 1) * 16;
    const int nbase = (w >> 1) * 4;

    constexpr int C8 = K / 8;
    for (int idx = tid; idx < 128 * C8; idx += 256) {
        int nn = idx / C8, c8 = idx % C8;
        *reinterpret_cast<uint4*>(&Wt[nn * PA + c8 * 8]) =
            *reinterpret_cast<const uint4*>(&Wpre[nn * K + c8 * 8]);
    }
    float bcol[4];
    #pragma unroll
    for (int nt = 0; nt < 4; nt++) bcol[nt] = bias[(nbase + nt) * 16 + l16];
    float csum[4] = {0.f, 0.f, 0.f, 0.f}, csq[4] = {0.f, 0.f, 0.f, 0.f};

    for (int tile = blockIdx.x; tile < ntiles; tile += gridDim.x) {
        const int row0 = tile * 32;
        __syncthreads();
        for (int cid = tid; cid < 32 * C8; cid += 256) {
            int row = cid / C8, c8 = cid % C8;
            int r = row0 + row;
            uint4 h, l;
            if (r < N) {
                h = *reinterpret_cast<const uint4*>(&Ah[(size_t)r * K + c8 * 8]);
                l = *reinterpret_cast<const uint4*>(&Al[(size_t)r * K + c8 * 8]);
            } else {
                h = make_uint4(0u,0u,0u,0u);
                l = make_uint4(0u,0u,0u,0u);
            }
            *reinterpret_cast<uint4*>(&As_hi[row * PA + c8 * 8]) = h;
            *reinterpret_cast<uint4*>(&As_lo[row * PA + c8 * 8]) = l;
        }
        __syncthreads();

        f32x4 acc[4];
        #pragma unroll
        for (int nt = 0; nt < 4; nt++) { f32x4 z = {0.f,0.f,0.f,0.f}; acc[nt] = z; }
        #pragma unroll
        for (int chunk = 0; chunk < K / 32; chunk++) {
            short8_t ahi = *reinterpret_cast<const short8_t*>(
                &As_hi[(rbase + l16) * PA + chunk * 32 + quad * 8]);
            short8_t alo = *reinterpret_cast<const short8_t*>(
                &As_lo[(rbase + l16) * PA + chunk * 32 + quad * 8]);
            #pragma unroll
            for (int nt = 0; nt < 4; nt++) {
                short8_t bfr = *reinterpret_cast<const short8_t*>(
                    &Wt[((nbase + nt) * 16 + l16) * PA + chunk * 32 + quad * 8]);
                acc[nt] = __builtin_amdgcn_mfma_f32_16x16x32_bf16(alo, bfr, acc[nt], 0, 0, 0);
                acc[nt] = __builtin_amdgcn_mfma_f32_16x16x32_bf16(ahi, bfr, acc[nt], 0, 0, 0);
            }
        }
        const int rb = row0 + rbase + quad * 4;
        #pragma unroll
        for (int nt = 0; nt < 4; nt++) {
            #pragma unroll
            for (int rg = 0; rg < 4; rg++) {
                int r = rb + rg;
                if (r < N) {
                    float v = acc[nt][rg] + bcol[nt];
                    out[(size_t)r * 128 + (nbase + nt) * 16 + l16] = v;
                    csum[nt] += v; csq[nt] += v * v;
                }
            }
        }
    }
    #pragma unroll
    for (int nt = 0; nt < 4; nt++) {
        float s = csum[nt]; s += __shfl_xor(s, 16); s += __shfl_xor(s, 32);
        float q = csq[nt];  q += __shfl_xor(q, 16); q += __shfl_xor(q, 32);
        if (quad == 0) {
            int col = (nbase + nt) * 16 + l16;
            atomicAdd(&stats_out[col], s);
            atomicAdd(&stats_out[128 + col], q);
        }
    }
}

// ================================================================ MFMA GEMM with fused BN at staging
// out[N,128] = lrelu(bn(A)) @ W + bias, BN params from raw stats_in.
// In-place safe (out==A). Stats of out -> stats_out. W pre-converted bf16.
__global__ __launch_bounds__(256, 3) void gemm_bn_mfma_kernel(
    const float* __restrict__ A,
    const float* __restrict__ stats_in, const float* __restrict__ g,
    const float* __restrict__ be, float invN,
    const unsigned short* __restrict__ Wpre, const float* __restrict__ bias,
    float* __restrict__ out, float* __restrict__ stats_out, int N, int ntiles)
{
    constexpr int K = 128;
    constexpr int PA = K + 8;
    __shared__ unsigned short As_hi[32 * PA];
    __shared__ unsigned short As_lo[32 * PA];
    __shared__ unsigned short Wt[128 * PA];
    __shared__ float scale_s[K];
    __shared__ float shift_s[K];
    const int tid = threadIdx.x;
    const int w = tid >> 6;
    const int lane = tid & 63;
    const int quad = lane >> 4;
    const int l16 = lane & 15;
    const int rbase = (w & 1) * 16;
    const int nbase = (w >> 1) * 4;

    constexpr int C8 = K / 8;
    for (int idx = tid; idx < 128 * C8; idx += 256) {
        int nn = idx / C8, c8 = idx % C8;
        *reinterpret_cast<uint4*>(&Wt[nn * PA + c8 * 8]) =
            *reinterpret_cast<const uint4*>(&Wpre[nn * K + c8 * 8]);
    }
    for (int i = tid; i < K; i += 256) {
        float m = stats_in[i] * invN;
        float va = fmaxf(stats_in[K + i] * invN - m * m, 0.f);
        float sc = g[i] * rsqrtf(va + 1e-5f);
        scale_s[i] = sc;
        shift_s[i] = be[i] - m * sc;
    }
    float bcol[4];
    #pragma unroll
    for (int nt = 0; nt < 4; nt++) bcol[nt] = bias[(nbase + nt) * 16 + l16];
    float csum[4] = {0.f, 0.f, 0.f, 0.f}, csq[4] = {0.f, 0.f, 0.f, 0.f};

    for (int tile = blockIdx.x; tile < ntiles; tile += gridDim.x) {
        const int row0 = tile * 32;
        __syncthreads();
        for (int cid = tid; cid < 32 * C8; cid += 256) {
            int row = cid / C8, c8 = cid % C8;
            int r = row0 + row;
            float f[8];
            if (r < N) {
                float4 u0 = *reinterpret_cast<const float4*>(&A[(size_t)r * K + c8 * 8]);
                float4 u1 = *reinterpret_cast<const float4*>(&A[(size_t)r * K + c8 * 8 + 4]);
                f[0]=u0.x; f[1]=u0.y; f[2]=u0.z; f[3]=u0.w;
                f[4]=u1.x; f[5]=u1.y; f[6]=u1.z; f[7]=u1.w;
            } else {
                #pragma unroll
                for (int j = 0; j < 8; j++) f[j] = 0.f;
            }
            int kb = c8 * 8;
            #pragma unroll
            for (int j = 0; j < 8; j++)
                f[j] = lrelu(fmaf(f[j], scale_s[kb + j], shift_s[kb + j]));
            unsigned int hi[4], lo[4];
            #pragma unroll
            for (int j = 0; j < 4; j++) {
                unsigned int b0 = __float_as_uint(f[2*j]);
                unsigned int b1 = __float_as_uint(f[2*j + 1]);
                hi[j] = __builtin_amdgcn_perm(b1, b0, 0x07060302u);
                float l0 = f[2*j]     - __uint_as_float(b0 & 0xffff0000u);
                float l1 = f[2*j + 1] - __uint_as_float(b1 & 0xffff0000u);
                lo[j] = __builtin_amdgcn_perm(__float_as_uint(l1), __float_as_uint(l0), 0x07060302u);
            }
            *reinterpret_cast<uint4*>(&As_hi[row * PA + c8 * 8]) = make_uint4(hi[0], hi[1], hi[2], hi[3]);
            *reinterpret_cast<uint4*>(&As_lo[row * PA + c8 * 8]) = make_uint4(lo[0], lo[1], lo[2], lo[3]);
        }
        __syncthreads();

        f32x4 acc[4];
        #pragma unroll
        for (int nt = 0; nt < 4; nt++) { f32x4 z = {0.f,0.f,0.f,0.f}; acc[nt] = z; }
        #pragma unroll
        for (int chunk = 0; chunk < K / 32; chunk++) {
            short8_t ahi = *reinterpret_cast<const short8_t*>(
                &As_hi[(rbase + l16) * PA + chunk * 32 + quad * 8]);
            short8_t alo = *reinterpret_cast<const short8_t*>(
                &As_lo[(rbase + l16) * PA + chunk * 32 + quad * 8]);
            #pragma unroll
            for (int nt = 0; nt < 4; nt++) {
                short8_t bfr = *reinterpret_cast<const short8_t*>(
                    &Wt[((nbase + nt) * 16 + l16) * PA + chunk * 32 + quad * 8]);
                acc[nt] = __builtin_amdgcn_mfma_f32_16x16x32_bf16(alo, bfr, acc[nt], 0, 0, 0);
                acc[nt] = __builtin_amdgcn_mfma_f32_16x16x32_bf16(ahi, bfr, acc[nt], 0, 0, 0);
            }
        }
        const int rb = row0 + rbase + quad * 4;
        #pragma unroll
        for (int nt = 0; nt < 4; nt++) {
            #pragma unroll
            for (int rg = 0; rg < 4; rg++) {
                int r = rb + rg;
                if (r < N) {
                    float v = acc[nt][rg] + bcol[nt];
                    out[(size_t)r * 128 + (nbase + nt) * 16 + l16] = v;
                    csum[nt] += v; csq[nt] += v * v;
                }
            }
        }
    }
    #pragma unroll
    for (int nt = 0; nt < 4; nt++) {
        float s = csum[nt]; s += __shfl_xor(s, 16); s += __shfl_xor(s, 32);
        float q = csq[nt];  q += __shfl_xor(q, 16); q += __shfl_xor(q, 32);
        if (quad == 0) {
            int col = (nbase + nt) * 16 + l16;
            atomicAdd(&stats_out[col], s);
            atomicAdd(&stats_out[128 + col], q);
        }
    }
}

// ================================================================ global add pool (BN fused)
__global__ __launch_bounds__(256) void pool_kernel_bn(
    const float* __restrict__ U, const int* __restrict__ batch,
    const float* __restrict__ stats, const float* __restrict__ g,
    const float* __restrict__ be, float invN,
    float* __restrict__ pool, int N)
{
    int w = (blockIdx.x * 256 + threadIdx.x) >> 6;
    int lane = threadIdx.x & 63;
    int n0 = w * 32;
    if (n0 >= N) return;
    int n1 = min(n0 + 32, N);
    int c0 = lane * 2;
    float sc0, sh0, sc1, sh1;
    {
        float m0 = stats[c0] * invN;
        float v0 = fmaxf(stats[128 + c0] * invN - m0 * m0, 0.f);
        sc0 = g[c0] * rsqrtf(v0 + 1e-5f);
        sh0 = be[c0] - m0 * sc0;
        float m1 = stats[c0 + 1] * invN;
        float v1 = fmaxf(stats[128 + c0 + 1] * invN - m1 * m1, 0.f);
        sc1 = g[c0 + 1] * rsqrtf(v1 + 1e-5f);
        sh1 = be[c0 + 1] - m1 * sc1;
    }
    float a0 = 0.f, a1 = 0.f;
    int cur = batch[n0];
    for (int n = n0; n < n1; ++n) {
        int b = batch[n];
        if (b != cur) {
            atomicAdd(&pool[(size_t)cur * 128 + c0], a0);
            atomicAdd(&pool[(size_t)cur * 128 + c0 + 1], a1);
            a0 = a1 = 0.f; cur = b;
        }
        float2 v = *reinterpret_cast<const float2*>(&U[(size_t)n * 128 + c0]);
        a0 += lrelu(fmaf(v.x, sc0, sh0));
        a1 += lrelu(fmaf(v.y, sc1, sh1));
    }
    atomicAdd(&pool[(size_t)cur * 128 + c0], a0);
    atomicAdd(&pool[(size_t)cur * 128 + c0 + 1], a1);
}

// ================================================================ final (BN fused)
__global__ __launch_bounds__(256) void final_kernel_bn(
    const float* __restrict__ U, const float* __restrict__ pool,
    const int* __restrict__ batch,
    const float* __restrict__ stats, const float* __restrict__ g,
    const float* __restrict__ be, float invN,
    const float* __restrict__ wf, const float* __restrict__ bf,
    float* __restrict__ out, int N)
{
    __shared__ float wf_s[512];
    int tid = threadIdx.x;
    for (int i = tid; i < 512; i += 256) wf_s[i] = wf[i];
    __syncthreads();
    int wid = tid >> 6, lane = tid & 63;
    int n = blockIdx.x * 4 + wid;
    if (n >= N) return;
    int cA = lane, cB = 64 + lane;
    float scA, shA, scB, shB;
    {
        float mA = stats[cA] * invN;
        float vA = fmaxf(stats[128 + cA] * invN - mA * mA, 0.f);
        scA = g[cA] * rsqrtf(vA + 1e-5f);
        shA = be[cA] - mA * scA;
        float mB = stats[cB] * invN;
        float vB = fmaxf(stats[128 + cB] * invN - mB * mB, 0.f);
        scB = g[cB] * rsqrtf(vB + 1e-5f);
        shB = be[cB] - mB * scB;
    }
    int b = batch[n];
    float v0 = lrelu(fmaf(U[(size_t)n * 128 + cA], scA, shA));
    float v1 = lrelu(fmaf(U[(size_t)n * 128 + cB], scB, shB));
    float p0 = pool[(size_t)b * 128 + cA];
    float p1 = pool[(size_t)b * 128 + cB];
    float a0 = v0 * wf_s[lane * 2]       + v1 * wf_s[(64 + lane) * 2]
             + p0 * wf_s[(128 + lane) * 2] + p1 * wf_s[(192 + lane) * 2];
    float a1 = v0 * wf_s[lane * 2 + 1]       + v1 * wf_s[(64 + lane) * 2 + 1]
             + p0 * wf_s[(128 + lane) * 2 + 1] + p1 * wf_s[(192 + lane) * 2 + 1];
    #pragma unroll
    for (int off = 32; off >= 1; off >>= 1) {
        a0 += __shfl_down(a0, off);
        a1 += __shfl_down(a1, off);
    }
    if (lane == 0) {
        a0 += bf[0]; a1 += bf[1];
        float mx = fmaxf(a0, a1);
        float e0 = __expf(a0 - mx), e1 = __expf(a1 - mx);
        float inv = 1.f / (e0 + e1);
        out[(size_t)n * 2]     = e0 * inv;
        out[(size_t)n * 2 + 1] = e1 * inv;
    }
}

// ================================================================ launch
extern "C" void kernel_launch(void* const* d_in, const int* in_sizes, int n_in,
                              void* d_out, int out_size, void* d_ws, size_t ws_size,
                              hipStream_t stream)
{
    const float* x0    = (const float*)d_in[0];
    const int*   ei    = (const int*)d_in[1];
    const float* ea    = (const float*)d_in[2];
    const int*   batch = (const int*)d_in[3];
    const int E = in_sizes[1] / 2;
    const int N = in_sizes[3];
    const int* srcv = ei;
    const int* dstv = ei + E;
    const float* wf = (const float*)d_in[37];
    const float* bfp = (const float*)d_in[38];
    float* out = (float*)d_out;
    const float invN = 1.0f / (float)N;
    const int ntiles = (N + 31) / 32;

    // ---- workspace layout (floats) ----
    const size_t base_f = (size_t)2 * N * 128 + (size_t)GNUM * 128 + 6 * 256
                        + (size_t)(N + 1) + (size_t)N + 128 + (size_t)E;
    const size_t full_f = base_f + (size_t)E * 16 + (size_t)E;
    const bool ro = (ws_size >= full_f * 4);

    float* ws = (float*)d_ws;
    size_t o = 0;
    float* xA    = ws + o; o += (size_t)N * 128;   // U buffer (fp32)
    float* xB    = ws + o; o += (size_t)N * 128;   // hi/lo plane space
    float* eap   = ws + o; o += ro ? (size_t)E * 16 : 0;
    float* poolb = ws + o; o += (size_t)GNUM * 128;
    float* statsb= ws + o; o += 6 * 256;
    int* srcp    = (int*)(ws + o); o += ro ? (size_t)E : 0;
    int* off     = (int*)(ws + o); o += (size_t)(N + 1);
    int* cursor  = (int*)(ws + o); o += (size_t)N;
    int* bsumb   = (int*)(ws + o); o += 128;
    int* perm    = (int*)(ws + o);

    // hi/lo bf16 planes live inside xB
    unsigned short* planeh = (unsigned short*)xB;
    // pre-converted W planes reuse the cursor region (dead after scatter;
    // 86016 shorts = 172 KB <= N*4 = 400 KB)
    unsigned short* wtbuf = (unsigned short*)cursor;

    // ---- CSR build (by destination) ----
    hipMemsetAsync(off, 0, (size_t)(N + 1) * sizeof(int), stream);
    hipMemsetAsync(statsb, 0, (size_t)6 * 256 * sizeof(float), stream);
    hipMemsetAsync(poolb, 0, (size_t)GNUM * 128 * sizeof(float), stream);
    hist_kernel<<<(E + 255) / 256, 256, 0, stream>>>(dstv, off, E);
    const int n1 = N + 1;
    const int nb = (n1 + 1023) / 1024;
    scan_block_kernel<<<nb, 256, 0, stream>>>(off, bsumb, n1);
    scan_carry_kernel<<<1, 128, 0, stream>>>(bsumb, nb);
    scan_add_kernel<<<(n1 + 255) / 256, 256, 0, stream>>>(off, bsumb, cursor, n1, N);
    if (ro)
        scatter_reorder_kernel<<<(E + 255) / 256, 256, 0, stream>>>(
            dstv, srcv, ea, cursor, eap, srcp, E);
    else
        scatter_kernel<<<(E + 255) / 256, 256, 0, stream>>>(dstv, cursor, perm, E);

    // ---- pre-convert W matrices (cursor region is dead now) ----
    wconv_kernel<<<(86016 + 255) / 256, 256, 0, stream>>>(
        (const float*)d_in[4 + 3], (const float*)d_in[4 + 7],
        (const float*)d_in[15 + 3], (const float*)d_in[15 + 7],
        (const float*)d_in[26 + 3], (const float*)d_in[26 + 7], wtbuf);
    const unsigned short* w1p[3] = { wtbuf, wtbuf + 4096 + 16384,
                                     wtbuf + 4096 + 3 * 16384 };
    const unsigned short* w2p[3] = { wtbuf + 4096, wtbuf + 4096 + 2 * 16384,
                                     wtbuf + 4096 + 4 * 16384 };

    const float* g_ea  = ro ? eap  : ea;
    const int*   g_src = ro ? srcp : srcv;
    const int gather_blocks = (N + 3) / 4;

    const float *pg = nullptr, *pbe = nullptr;
    float* pstats = nullptr;

    for (int l = 0; l < 3; l++) {
        const int C = (l == 0) ? 32 : 128;
        int bidx = 4 + l * 11;
        const float* epsp = (const float*)d_in[bidx + 0];
        const float* ew   = (const float*)d_in[bidx + 1];
        const float* eb   = (const float*)d_in[bidx + 2];
        const float* b1   = (const float*)d_in[bidx + 4];
        const float* g1   = (const float*)d_in[bidx + 5];
        const float* be1  = (const float*)d_in[bidx + 6];
        const float* b2   = (const float*)d_in[bidx + 8];
        const float* g2   = (const float*)d_in[bidx + 9];
        const float* be2  = (const float*)d_in[bidx + 10];
        float* st1 = statsb + (size_t)(l * 2) * 256;
        float* st2 = statsb + (size_t)(l * 2 + 1) * 256;

        unsigned short* ah = planeh;                     // hi plane [N*C]
        unsigned short* al = planeh + (size_t)N * C;     // lo plane [N*C]

        if (l == 0) {
            if (ro) gather_kernel32<true><<<gather_blocks, 256, 0, stream>>>(
                        g_ea, g_src, perm, off, ew, eb, epsp, x0, ah, al, N);
            else    gather_kernel32<false><<<gather_blocks, 256, 0, stream>>>(
                        g_ea, g_src, perm, off, ew, eb, epsp, x0, ah, al, N);
            gemm_copy_mfma_kernel<32><<<GEMM_GRID, 256, 0, stream>>>(
                ah, al, w1p[0], b1, xA, st1, N, ntiles);
        } else {
            if (ro) gather_kernel128_bn<true><<<gather_blocks, 256, 0, stream>>>(
                        g_ea, g_src, perm, off, ew, eb, epsp, xA,
                        pstats, pg, pbe, invN, ah, al, N);
            else    gather_kernel128_bn<false><<<gather_blocks, 256, 0, stream>>>(
                        g_ea, g_src, perm, off, ew, eb, epsp, xA,
                        pstats, pg, pbe, invN, ah, al, N);
            gemm_copy_mfma_kernel<128><<<GEMM_GRID, 256, 0, stream>>>(
                ah, al, w1p[l], b1, xA, st1, N, ntiles);
        }
        gemm_bn_mfma_kernel<<<GEMM_GRID, 256, 0, stream>>>(
            xA, st1, g1, be1, invN, w2p[l], b2, xA, st2, N, ntiles);
        pstats = st2; pg = g2; pbe = be2;
    }
    pool_kernel_bn<<<((N + 31) / 32 * 64 + 255) / 256, 256, 0, stream>>>(
        xA, batch, pstats, pg, pbe, invN, poolb, N);
    final_kernel_bn<<<(N + 3) / 4, 256, 0, stream>>>(
        xA, poolb, batch, pstats, pg, pbe, invN, wf, bfp, out, N);
}

// Round 16
// 1220.202 us; speedup vs baseline: 1.0575x; 1.0575x over previous
//
#include <hip/hip_runtime.h>

#define GEMM_GRID 512   // 2 blocks/CU; 768 measured +40us (R8) and +53us (R15, unconfounded)
#define GNUM 4096   // num graphs (fixed in reference)

typedef __attribute__((ext_vector_type(8))) short short8_t;
typedef __attribute__((ext_vector_type(4))) float f32x4;
typedef __attribute__((ext_vector_type(2))) float v2f;

__device__ __forceinline__ float bf2f(unsigned short u) {
    union { unsigned int i; float f; } v; v.i = ((unsigned int)u) << 16; return v.f;
}
__device__ __forceinline__ unsigned short f2bf(float f) {
    union { float f; unsigned int i; } v; v.f = f;
    unsigned int b = v.i + 0x7FFFu + ((v.i >> 16) & 1u);
    return (unsigned short)(b >> 16);
}
__device__ __forceinline__ float lrelu(float v) { return v > 0.f ? v : 0.01f * v; }

// ================================================================ CSR build
__global__ __launch_bounds__(256) void hist_kernel(
    const int* __restrict__ dstv, int* __restrict__ cnt, int E)
{
    int i = blockIdx.x * 256 + threadIdx.x;
    if (i < E) atomicAdd(&cnt[dstv[i] + 1], 1);
}

__global__ __launch_bounds__(256) void scan_block_kernel(
    int* __restrict__ data, int* __restrict__ bsum, int n)
{
    __shared__ int s[256];
    int tid = threadIdx.x;
    int base = blockIdx.x * 1024 + tid * 4;
    int v[4]; int run = 0;
    #pragma unroll
    for (int i = 0; i < 4; i++) {
        int x = (base + i < n) ? data[base + i] : 0;
        run += x; v[i] = run;
    }
    s[tid] = run; __syncthreads();
    for (int off = 1; off < 256; off <<= 1) {
        int t = (tid >= off) ? s[tid - off] : 0;
        __syncthreads();
        s[tid] += t;
        __syncthreads();
    }
    int excl = s[tid] - run;
    #pragma unroll
    for (int i = 0; i < 4; i++)
        if (base + i < n) data[base + i] = v[i] + excl;
    if (tid == 255) bsum[blockIdx.x] = s[255];
}

__global__ __launch_bounds__(128) void scan_carry_kernel(int* __restrict__ bsum, int nb)
{
    __shared__ int s[128];
    int tid = threadIdx.x;
    int orig = (tid < nb) ? bsum[tid] : 0;
    s[tid] = orig; __syncthreads();
    for (int off = 1; off < 128; off <<= 1) {
        int t = (tid >= off) ? s[tid - off] : 0;
        __syncthreads();
        s[tid] += t;
        __syncthreads();
    }
    if (tid < nb) bsum[tid] = s[tid] - orig;
}

__global__ __launch_bounds__(256) void scan_add_kernel(
    int* __restrict__ data, const int* __restrict__ bsum,
    int* __restrict__ cursor, int n, int N)
{
    int i = blockIdx.x * 256 + threadIdx.x;
    if (i < n) {
        int v = data[i] + bsum[i >> 10];
        data[i] = v;
        if (i < N) cursor[i] = v;
    }
}

// non-RO fallback: plain scatter producing perm
__global__ __launch_bounds__(256) void scatter_kernel(
    const int* __restrict__ dstv, int* __restrict__ cursor,
    int* __restrict__ perm, int E)
{
    int i = blockIdx.x * 256 + threadIdx.x;
    if (i < E) {
        int p = atomicAdd(&cursor[dstv[i]], 1);
        perm[p] = i;
    }
}

// RO path: fused scatter+reorder. Coalesced 64B ea read, scattered 64B write.
// PLAIN loads/stores (NT variants measured harmful: R12 stores, R13 loads).
__global__ __launch_bounds__(256) void scatter_reorder_kernel(
    const int* __restrict__ dstv, const int* __restrict__ srcv,
    const float* __restrict__ ea, int* __restrict__ cursor,
    float* __restrict__ eap, int* __restrict__ srcp, int E)
{
    int i = blockIdx.x * 256 + threadIdx.x;
    if (i >= E) return;
    int p = atomicAdd(&cursor[dstv[i]], 1);
    srcp[p] = srcv[i];
    const float4* s = reinterpret_cast<const float4*>(ea) + (size_t)i * 4;
    float4* d = reinterpret_cast<float4*>(eap) + (size_t)p * 4;
    float4 v0 = s[0], v1 = s[1], v2 = s[2], v3 = s[3];
    d[0] = v0; d[1] = v1; d[2] = v2; d[3] = v3;
}

// ================================================================ W pre-convert (bf16, transposed)
__global__ __launch_bounds__(256) void wconv_kernel(
    const float* __restrict__ w10, const float* __restrict__ w20,
    const float* __restrict__ w11, const float* __restrict__ w21,
    const float* __restrict__ w12, const float* __restrict__ w22,
    unsigned short* __restrict__ wt)
{
    int idx = blockIdx.x * 256 + threadIdx.x;
    if (idx < 4096) {
        int nn = idx >> 5, k = idx & 31;
        wt[idx] = f2bf(w10[k * 128 + nn]);
        return;
    }
    int r = idx - 4096;
    int seg = r >> 14;
    if (seg >= 5) return;
    int o = r & 16383;
    int nn = o >> 7, k = o & 127;
    const float* w = (seg == 0) ? w20 : (seg == 1) ? w11 : (seg == 2) ? w21
                   : (seg == 3) ? w12 : w22;
    wt[4096 + seg * 16384 + o] = f2bf(w[k * 128 + nn]);
    (void)nn;
}

// ================================================================ BN+lrelu pre-activation -> bf16 plane
// B[n][c] = f2bf(lrelu(bn(U[n][c]))). One pass (76MB traffic ~12us) replaces
// per-edge BN (done ~20x per source row) and HALVES the gather's scattered
// read bytes (512B fp32 row -> 256B bf16 row).
__global__ __launch_bounds__(256) void bnact_kernel(
    const float* __restrict__ U, const float* __restrict__ stats,
    const float* __restrict__ g, const float* __restrict__ be, float invN,
    unsigned short* __restrict__ B, int N)
{
    int idx = blockIdx.x * 256 + threadIdx.x;   // one thread per 8 channels
    if (idx >= N * 16) return;
    int n = idx >> 4;
    int c8 = (idx & 15) * 8;
    float4 u0 = *reinterpret_cast<const float4*>(&U[(size_t)n * 128 + c8]);
    float4 u1 = *reinterpret_cast<const float4*>(&U[(size_t)n * 128 + c8 + 4]);
    float f[8] = {u0.x, u0.y, u0.z, u0.w, u1.x, u1.y, u1.z, u1.w};
    unsigned int pk[4];
    #pragma unroll
    for (int j = 0; j < 4; j++) {
        unsigned short r0, r1;
        {
            int c = c8 + 2 * j;
            float m = stats[c] * invN;
            float v = fmaxf(stats[128 + c] * invN - m * m, 0.f);
            float sc = g[c] * rsqrtf(v + 1e-5f);
            r0 = f2bf(lrelu(fmaf(f[2*j], sc, be[c] - m * sc)));
        }
        {
            int c = c8 + 2 * j + 1;
            float m = stats[c] * invN;
            float v = fmaxf(stats[128 + c] * invN - m * m, 0.f);
            float sc = g[c] * rsqrtf(v + 1e-5f);
            r1 = f2bf(lrelu(fmaf(f[2*j+1], sc, be[c] - m * sc)));
        }
        pk[j] = (unsigned int)r0 | ((unsigned int)r1 << 16);
    }
    *reinterpret_cast<uint4*>(&B[(size_t)n * 128 + c8]) =
        make_uint4(pk[0], pk[1], pk[2], pk[3]);
}

// ================================================================ gather, layer 0 (C=32, raw x0)
// 32-edge chunk, one latency exposure per chunk (Round-3 winner).
template<bool RO>
__global__ __launch_bounds__(256) void gather_kernel32(
    const float* __restrict__ ea, const int* __restrict__ srcv,
    const int* __restrict__ perm, const int* __restrict__ off,
    const float* __restrict__ ew, const float* __restrict__ ebias,
    const float* __restrict__ epsp, const float* __restrict__ x,
    unsigned short* __restrict__ aggh, unsigned short* __restrict__ aggl, int N)
{
    __shared__ float ebuf[4][32 * 16];     // per-wave 2 KB ea staging
    const int tid = threadIdx.x;
    const int wv = tid >> 6;
    const int lane = tid & 63;
    int n = __builtin_amdgcn_readfirstlane((int)((blockIdx.x * 256 + tid) >> 6));
    if (n >= N) return;
    const int h = lane >> 5;               // half-wave: 0 -> edges 0-15, 1 -> 16-31
    const int c = lane & 31;               // channel
    float ewr[16];
    #pragma unroll
    for (int k = 0; k < 16; k++) ewr[k] = ew[k * 32 + c];
    const float ebr = ebias[c];
    const float xself = x[(size_t)n * 32 + c];
    float acc = 0.f;
    const int p0 = off[n], end = off[n + 1];
    float* eb_ = ebuf[wv];
    const float4* eaq = reinterpret_cast<const float4*>(ea);

    for (int p = p0; p < end; p += 32) {
        // ---- phase 1: index loads (broadcast per half) + cooperative ea loads
        int sv[16];
        #pragma unroll
        for (int j = 0; j < 16; j++) {
            int pj = min(p + h * 16 + j, end - 1);
            int e = RO ? pj : perm[pj];
            sv[j] = srcv[e];
        }
        int rowA = min(p + (lane >> 2), end - 1);
        int rowB = min(p + 16 + (lane >> 2), end - 1);
        int erA = RO ? rowA : perm[rowA];
        int erB = RO ? rowB : perm[rowB];
        float4 eaA = eaq[(size_t)erA * 4 + (lane & 3)];
        float4 eaB = eaq[(size_t)erB * 4 + (lane & 3)];
        __builtin_amdgcn_sched_barrier(0);
        // ---- phase 2: batched x row loads (16 independent, coalesced)
        float xv[16];
        #pragma unroll
        for (int j = 0; j < 16; j++)
            xv[j] = x[(size_t)sv[j] * 32 + c];
        __builtin_amdgcn_sched_barrier(0);
        // ---- phase 3: stage ea to LDS (same-wave: fence, no barrier)
        __threadfence_block();
        *reinterpret_cast<float4*>(&eb_[(lane >> 2) * 16 + (lane & 3) * 4]) = eaA;
        *reinterpret_cast<float4*>(&eb_[(16 + (lane >> 2)) * 16 + (lane & 3) * 4]) = eaB;
        __threadfence_block();
        // ---- phase 4: compute 16 edges (this half's rows)
        #pragma unroll
        for (int j = 0; j < 16; j++) {
            int row = h * 16 + j;
            const float4* er4 = reinterpret_cast<const float4*>(&eb_[row * 16]);
            float4 e0 = er4[0], e1 = er4[1], e2 = er4[2], e3 = er4[3];
            float u = ebr;
            u = fmaf(e0.x, ewr[0], u);  u = fmaf(e0.y, ewr[1], u);
            u = fmaf(e0.z, ewr[2], u);  u = fmaf(e0.w, ewr[3], u);
            u = fmaf(e1.x, ewr[4], u);  u = fmaf(e1.y, ewr[5], u);
            u = fmaf(e1.z, ewr[6], u);  u = fmaf(e1.w, ewr[7], u);
            u = fmaf(e2.x, ewr[8], u);  u = fmaf(e2.y, ewr[9], u);
            u = fmaf(e2.z, ewr[10], u); u = fmaf(e2.w, ewr[11], u);
            u = fmaf(e3.x, ewr[12], u); u = fmaf(e3.y, ewr[13], u);
            u = fmaf(e3.z, ewr[14], u); u = fmaf(e3.w, ewr[15], u);
            bool valid = (p + row) < end;
            acc += valid ? fmaxf(xv[j] + u, 0.f) : 0.f;
        }
    }
    acc += __shfl_xor(acc, 32);
    if (lane < 32) {
        float s = 1.f + epsp[0];
        float f = fmaf(xself, s, acc);
        unsigned int b = __float_as_uint(f);
        unsigned short hi = (unsigned short)(b >> 16);
        float lo = f - __uint_as_float(b & 0xffff0000u);
        aggh[(size_t)n * 32 + c] = hi;
        aggl[(size_t)n * 32 + c] = f2bf(lo);
    }
}

// ================================================================ gather, layers 1/2 (C=128), RO path
// Reads pre-activated bf16 plane B (256B/row scattered vs 512B fp32):
// halves the dominant scattered traffic; per-edge BN math eliminated.
// bf16 decode is 2 bit-ops/pair (hi = AND, lo = SHL).
__global__ __launch_bounds__(256) void gather_kernel128_b(
    const float* __restrict__ ea, const int* __restrict__ srcv,
    const int* __restrict__ off,
    const float* __restrict__ ew, const float* __restrict__ ebias,
    const float* __restrict__ epsp, const unsigned short* __restrict__ B,
    unsigned short* __restrict__ aggh, unsigned short* __restrict__ aggl, int N)
{
    int lane = threadIdx.x & 63;
    int n = __builtin_amdgcn_readfirstlane((int)((blockIdx.x * 256 + threadIdx.x) >> 6));
    if (n >= N) return;
    const int c0 = lane * 2;
    v2f ewv[16];
    #pragma unroll
    for (int k = 0; k < 16; k++)
        ewv[k] = *reinterpret_cast<const v2f*>(&ew[k * 128 + c0]);
    const v2f ebv = *reinterpret_cast<const v2f*>(&ebias[c0]);
    unsigned int bs = *reinterpret_cast<const unsigned int*>(&B[(size_t)n * 128 + c0]);
    v2f xnb;
    xnb.x = __uint_as_float(bs << 16);
    xnb.y = __uint_as_float(bs & 0xffff0000u);
    v2f acc = {0.f, 0.f};
    const int p0 = off[n];
    const int end = off[n + 1];
    const int endm1 = end - 1;
    for (int p = p0; p < end; p += 4) {
        int ss[4]; bool vv[4];
        #pragma unroll
        for (int j = 0; j < 4; j++) {
            int pj = p + j;
            vv[j] = pj < end;
            ss[j] = srcv[min(pj, endm1)];
        }
        float4 at[4][4];
        #pragma unroll
        for (int j = 0; j < 4; j++) {
            const float4* ap = reinterpret_cast<const float4*>(
                ea + (size_t)min(p + j, endm1) * 16);
            #pragma unroll
            for (int q = 0; q < 4; q++) at[j][q] = ap[q];
        }
        unsigned int xb[4];
        #pragma unroll
        for (int j = 0; j < 4; j++)
            xb[j] = *reinterpret_cast<const unsigned int*>(&B[(size_t)ss[j] * 128 + c0]);
        __builtin_amdgcn_sched_barrier(0);   // pin: all loads issue before compute
        #pragma unroll
        for (int j = 0; j < 4; j++) {
            float av[16];
            #pragma unroll
            for (int q = 0; q < 4; q++) {
                av[4*q] = at[j][q].x; av[4*q+1] = at[j][q].y;
                av[4*q+2] = at[j][q].z; av[4*q+3] = at[j][q].w;
            }
            v2f xv;
            xv.x = __uint_as_float(xb[j] << 16);
            xv.y = __uint_as_float(xb[j] & 0xffff0000u);
            v2f u = ebv;
            #pragma unroll
            for (int k = 0; k < 16; k++) u = ewv[k] * av[k] + u;
            v2f m = xv + u;
            m.x = fmaxf(m.x, 0.f); m.y = fmaxf(m.y, 0.f);
            acc.x += vv[j] ? m.x : 0.f;
            acc.y += vv[j] ? m.y : 0.f;
        }
    }
    float s = 1.f + epsp[0];
    v2f o = xnb * s + acc;
    // split-pack: hi = trunc-top16, lo = residual (RNE)
    unsigned int b0 = __float_as_uint(o.x);
    unsigned int b1 = __float_as_uint(o.y);
    unsigned int hp = __builtin_amdgcn_perm(b1, b0, 0x07060302u);
    float l0 = o.x - __uint_as_float(b0 & 0xffff0000u);
    float l1 = o.y - __uint_as_float(b1 & 0xffff0000u);
    unsigned int lp = (unsigned int)f2bf(l0) | ((unsigned int)f2bf(l1) << 16);
    *reinterpret_cast<unsigned int*>(&aggh[(size_t)n * 128 + c0]) = hp;
    *reinterpret_cast<unsigned int*>(&aggl[(size_t)n * 128 + c0]) = lp;
}

// ================================================================ gather, layers 1/2 (C=128), non-RO fallback
// (fp32 U + per-edge BN, perm indirection -- unchanged known-good path)
__global__ __launch_bounds__(256) void gather_kernel128_bn(
    const float* __restrict__ ea, const int* __restrict__ srcv,
    const int* __restrict__ perm, const int* __restrict__ off,
    const float* __restrict__ ew, const float* __restrict__ ebias,
    const float* __restrict__ epsp, const float* __restrict__ U,
    const float* __restrict__ stats, const float* __restrict__ g,
    const float* __restrict__ be, float invN,
    unsigned short* __restrict__ aggh, unsigned short* __restrict__ aggl, int N)
{
    int lane = threadIdx.x & 63;
    int n = __builtin_amdgcn_readfirstlane((int)((blockIdx.x * 256 + threadIdx.x) >> 6));
    if (n >= N) return;
    const int c0 = lane * 2;
    v2f scv, shv;
    {
        float m0 = stats[c0] * invN;
        float v0 = fmaxf(stats[128 + c0] * invN - m0 * m0, 0.f);
        scv.x = g[c0] * rsqrtf(v0 + 1e-5f);
        shv.x = be[c0] - m0 * scv.x;
        float m1 = stats[c0 + 1] * invN;
        float v1 = fmaxf(stats[128 + c0 + 1] * invN - m1 * m1, 0.f);
        scv.y = g[c0 + 1] * rsqrtf(v1 + 1e-5f);
        shv.y = be[c0 + 1] - m1 * scv.y;
    }
    v2f ewv[16];
    #pragma unroll
    for (int k = 0; k < 16; k++)
        ewv[k] = *reinterpret_cast<const v2f*>(&ew[k * 128 + c0]);
    const v2f ebv = *reinterpret_cast<const v2f*>(&ebias[c0]);
    const v2f xn = *reinterpret_cast<const v2f*>(&U[(size_t)n * 128 + c0]);
    v2f acc = {0.f, 0.f};
    const int p0 = off[n];
    const int end = off[n + 1];
    for (int p = p0; p < end; p += 4) {
        int ee[4]; bool vv[4];
        #pragma unroll
        for (int j = 0; j < 4; j++) {
            int pj = p + j;
            vv[j] = pj < end;
            int ij = vv[j] ? pj : p;
            ee[j] = perm[ij];
        }
        int ss[4];
        #pragma unroll
        for (int j = 0; j < 4; j++) ss[j] = srcv[ee[j]];
        float4 at[4][4];
        #pragma unroll
        for (int j = 0; j < 4; j++) {
            const float4* ap = reinterpret_cast<const float4*>(ea + (size_t)ee[j] * 16);
            #pragma unroll
            for (int q = 0; q < 4; q++) at[j][q] = ap[q];
        }
        v2f xv[4];
        #pragma unroll
        for (int j = 0; j < 4; j++)
            xv[j] = *reinterpret_cast<const v2f*>(&U[(size_t)ss[j] * 128 + c0]);
        __builtin_amdgcn_sched_barrier(0);
        #pragma unroll
        for (int j = 0; j < 4; j++) {
            float av[16];
            #pragma unroll
            for (int q = 0; q < 4; q++) {
                av[4*q] = at[j][q].x; av[4*q+1] = at[j][q].y;
                av[4*q+2] = at[j][q].z; av[4*q+3] = at[j][q].w;
            }
            v2f xb = xv[j] * scv + shv;
            xb.x = lrelu(xb.x); xb.y = lrelu(xb.y);
            v2f u = ebv;
            #pragma unroll
            for (int k = 0; k < 16; k++) u = ewv[k] * av[k] + u;
            v2f m = xb + u;
            m.x = fmaxf(m.x, 0.f); m.y = fmaxf(m.y, 0.f);
            acc.x += vv[j] ? m.x : 0.f;
            acc.y += vv[j] ? m.y : 0.f;
        }
    }
    v2f xnb = xn * scv + shv;
    xnb.x = lrelu(xnb.x); xnb.y = lrelu(xnb.y);
    float s = 1.f + epsp[0];
    v2f o = xnb * s + acc;
    unsigned int b0 = __float_as_uint(o.x);
    unsigned int b1 = __float_as_uint(o.y);
    unsigned int hp = __builtin_amdgcn_perm(b1, b0, 0x07060302u);
    float l0 = o.x - __uint_as_float(b0 & 0xffff0000u);
    float l1 = o.y - __uint_as_float(b1 & 0xffff0000u);
    unsigned int lp = (unsigned int)f2bf(l0) | ((unsigned int)f2bf(l1) << 16);
    *reinterpret_cast<unsigned int*>(&aggh[(size_t)n * 128 + c0]) = hp;
    *reinterpret_cast<unsigned int*>(&aggl[(size_t)n * 128 + c0]) = lp;
}

// ================================================================ MFMA GEMM, copy-staged (pre-split A)
template<int K>
__global__ __launch_bounds__(256, 3) void gemm_copy_mfma_kernel(
    const unsigned short* __restrict__ Ah, const unsigned short* __restrict__ Al,
    const unsigned short* __restrict__ Wpre, const float* __restrict__ bias,
    float* __restrict__ out, float* __restrict__ stats_out, int N, int ntiles)
{
    constexpr int PA = K + 8;
    __shared__ unsigned short As_hi[32 * PA];
    __shared__ unsigned short As_lo[32 * PA];
    __shared__ unsigned short Wt[128 * PA];
    const int tid = threadIdx.x;
    const int w = tid >> 6;
    const int lane = tid & 63;
    const int quad = lane >> 4;
    const int l16 = lane & 15;
    const int rbase = (w & 1) * 16;
    const int nbase = (w >> 1) * 4;

    constexpr int C8 = K / 8;
    for (int idx = tid; idx < 128 * C8; idx += 256) {
        int nn = idx / C8, c8 = idx % C8;
        *reinterpret_cast<uint4*>(&Wt[nn * PA + c8 * 8]) =
            *reinterpret_cast<const uint4*>(&Wpre[nn * K + c8 * 8]);
    }
    float bcol[4];
    #pragma unroll
    for (int nt = 0; nt < 4; nt++) bcol[nt] = bias[(nbase + nt) * 16 + l16];
    float csum[4] = {0.f, 0.f, 0.f, 0.f}, csq[4] = {0.f, 0.f, 0.f, 0.f};

    for (int tile = blockIdx.x; tile < ntiles; tile += gridDim.x) {
        const int row0 = tile * 32;
        __syncthreads();
        for (int cid = tid; cid < 32 * C8; cid += 256) {
            int row = cid / C8, c8 = cid % C8;
            int r = row0 + row;
            uint4 h, l;
            if (r < N) {
                h = *reinterpret_cast<const uint4*>(&Ah[(size_t)r * K + c8 * 8]);
                l = *reinterpret_cast<const uint4*>(&Al[(size_t)r * K + c8 * 8]);
            } else {
                h = make_uint4(0u,0u,0u,0u);
                l = make_uint4(0u,0u,0u,0u);
            }
            *reinterpret_cast<uint4*>(&As_hi[row * PA + c8 * 8]) = h;
            *reinterpret_cast<uint4*>(&As_lo[row * PA + c8 * 8]) = l;
        }
        __syncthreads();

        f32x4 acc[4];
        #pragma unroll
        for (int nt = 0; nt < 4; nt++) { f32x4 z = {0.f,0.f,0.f,0.f}; acc[nt] = z; }
        #pragma unroll
        for (int chunk = 0; chunk < K / 32; chunk++) {
            short8_t ahi = *reinterpret_cast<const short8_t*>(
                &As_hi[(rbase + l16) * PA + chunk * 32 + quad * 8]);
            short8_t alo = *reinterpret_cast<const short8_t*>(
                &As_lo[(rbase + l16) * PA + chunk * 32 + quad * 8]);
            #pragma unroll
            for (int nt = 0; nt < 4; nt++) {
                short8_t bfr = *reinterpret_cast<const short8_t*>(
                    &Wt[((nbase + nt) * 16 + l16) * PA + chunk * 32 + quad * 8]);
                acc[nt] = __builtin_amdgcn_mfma_f32_16x16x32_bf16(alo, bfr, acc[nt], 0, 0, 0);
                acc[nt] = __builtin_amdgcn_mfma_f32_16x16x32_bf16(ahi, bfr, acc[nt], 0, 0, 0);
            }
        }
        const int rb = row0 + rbase + quad * 4;
        #pragma unroll
        for (int nt = 0; nt < 4; nt++) {
            #pragma unroll
            for (int rg = 0; rg < 4; rg++) {
                int r = rb + rg;
                if (r < N) {
                    float v = acc[nt][rg] + bcol[nt];
                    out[(size_t)r * 128 + (nbase + nt) * 16 + l16] = v;
                    csum[nt] += v; csq[nt] += v * v;
                }
            }
        }
    }
    #pragma unroll
    for (int nt = 0; nt < 4; nt++) {
        float s = csum[nt]; s += __shfl_xor(s, 16); s += __shfl_xor(s, 32);
        float q = csq[nt];  q += __shfl_xor(q, 16); q += __shfl_xor(q, 32);
        if (quad == 0) {
            int col = (nbase + nt) * 16 + l16;
            atomicAdd(&stats_out[col], s);
            atomicAdd(&stats_out[128 + col], q);
        }
    }
}

// ================================================================ MFMA GEMM with fused BN at staging
__global__ __launch_bounds__(256, 3) void gemm_bn_mfma_kernel(
    const float* __restrict__ A,
    const float* __restrict__ stats_in, const float* __restrict__ g,
    const float* __restrict__ be, float invN,
    const unsigned short* __restrict__ Wpre, const float* __restrict__ bias,
    float* __restrict__ out, float* __restrict__ stats_out, int N, int ntiles)
{
    constexpr int K = 128;
    constexpr int PA = K + 8;
    __shared__ unsigned short As_hi[32 * PA];
    __shared__ unsigned short As_lo[32 * PA];
    __shared__ unsigned short Wt[128 * PA];
    __shared__ float scale_s[K];
    __shared__ float shift_s[K];
    const int tid = threadIdx.x;
    const int w = tid >> 6;
    const int lane = tid & 63;
    const int quad = lane >> 4;
    const int l16 = lane & 15;
    const int rbase = (w & 1) * 16;
    const int nbase = (w >> 1) * 4;

    constexpr int C8 = K / 8;
    for (int idx = tid; idx < 128 * C8; idx += 256) {
        int nn = idx / C8, c8 = idx % C8;
        *reinterpret_cast<uint4*>(&Wt[nn * PA + c8 * 8]) =
            *reinterpret_cast<const uint4*>(&Wpre[nn * K + c8 * 8]);
    }
    for (int i = tid; i < K; i += 256) {
        float m = stats_in[i] * invN;
        float va = fmaxf(stats_in[K + i] * invN - m * m, 0.f);
        float sc = g[i] * rsqrtf(va + 1e-5f);
        scale_s[i] = sc;
        shift_s[i] = be[i] - m * sc;
    }
    float bcol[4];
    #pragma unroll
    for (int nt = 0; nt < 4; nt++) bcol[nt] = bias[(nbase + nt) * 16 + l16];
    float csum[4] = {0.f, 0.f, 0.f, 0.f}, csq[4] = {0.f, 0.f, 0.f, 0.f};

    for (int tile = blockIdx.x; tile < ntiles; tile += gridDim.x) {
        const int row0 = tile * 32;
        __syncthreads();
        for (int cid = tid; cid < 32 * C8; cid += 256) {
            int row = cid / C8, c8 = cid % C8;
            int r = row0 + row;
            float f[8];
            if (r < N) {
                float4 u0 = *reinterpret_cast<const float4*>(&A[(size_t)r * K + c8 * 8]);
                float4 u1 = *reinterpret_cast<const float4*>(&A[(size_t)r * K + c8 * 8 + 4]);
                f[0]=u0.x; f[1]=u0.y; f[2]=u0.z; f[3]=u0.w;
                f[4]=u1.x; f[5]=u1.y; f[6]=u1.z; f[7]=u1.w;
            } else {
                #pragma unroll
                for (int j = 0; j < 8; j++) f[j] = 0.f;
            }
            int kb = c8 * 8;
            #pragma unroll
            for (int j = 0; j < 8; j++)
                f[j] = lrelu(fmaf(f[j], scale_s[kb + j], shift_s[kb + j]));
            unsigned int hi[4], lo[4];
            #pragma unroll
            for (int j = 0; j < 4; j++) {
                unsigned int b0 = __float_as_uint(f[2*j]);
                unsigned int b1 = __float_as_uint(f[2*j + 1]);
                hi[j] = __builtin_amdgcn_perm(b1, b0, 0x07060302u);
                float l0 = f[2*j]     - __uint_as_float(b0 & 0xffff0000u);
                float l1 = f[2*j + 1] - __uint_as_float(b1 & 0xffff0000u);
                lo[j] = __builtin_amdgcn_perm(__float_as_uint(l1), __float_as_uint(l0), 0x07060302u);
            }
            *reinterpret_cast<uint4*>(&As_hi[row * PA + c8 * 8]) = make_uint4(hi[0], hi[1], hi[2], hi[3]);
            *reinterpret_cast<uint4*>(&As_lo[row * PA + c8 * 8]) = make_uint4(lo[0], lo[1], lo[2], lo[3]);
        }
        __syncthreads();

        f32x4 acc[4];
        #pragma unroll
        for (int nt = 0; nt < 4; nt++) { f32x4 z = {0.f,0.f,0.f,0.f}; acc[nt] = z; }
        #pragma unroll
        for (int chunk = 0; chunk < K / 32; chunk++) {
            short8_t ahi = *reinterpret_cast<const short8_t*>(
                &As_hi[(rbase + l16) * PA + chunk * 32 + quad * 8]);
            short8_t alo = *reinterpret_cast<const short8_t*>(
                &As_lo[(rbase + l16) * PA + chunk * 32 + quad * 8]);
            #pragma unroll
            for (int nt = 0; nt < 4; nt++) {
                short8_t bfr = *reinterpret_cast<const short8_t*>(
                    &Wt[((nbase + nt) * 16 + l16) * PA + chunk * 32 + quad * 8]);
                acc[nt] = __builtin_amdgcn_mfma_f32_16x16x32_bf16(alo, bfr, acc[nt], 0, 0, 0);
                acc[nt] = __builtin_amdgcn_mfma_f32_16x16x32_bf16(ahi, bfr, acc[nt], 0, 0, 0);
            }
        }
        const int rb = row0 + rbase + quad * 4;
        #pragma unroll
        for (int nt = 0; nt < 4; nt++) {
            #pragma unroll
            for (int rg = 0; rg < 4; rg++) {
                int r = rb + rg;
                if (r < N) {
                    float v = acc[nt][rg] + bcol[nt];
                    out[(size_t)r * 128 + (nbase + nt) * 16 + l16] = v;
                    csum[nt] += v; csq[nt] += v * v;
                }
            }
        }
    }
    #pragma unroll
    for (int nt = 0; nt < 4; nt++) {
        float s = csum[nt]; s += __shfl_xor(s, 16); s += __shfl_xor(s, 32);
        float q = csq[nt];  q += __shfl_xor(q, 16); q += __shfl_xor(q, 32);
        if (quad == 0) {
            int col = (nbase + nt) * 16 + l16;
            atomicAdd(&stats_out[col], s);
            atomicAdd(&stats_out[128 + col], q);
        }
    }
}

// ================================================================ global add pool (BN fused)
__global__ __launch_bounds__(256) void pool_kernel_bn(
    const float* __restrict__ U, const int* __restrict__ batch,
    const float* __restrict__ stats, const float* __restrict__ g,
    const float* __restrict__ be, float invN,
    float* __restrict__ pool, int N)
{
    int w = (blockIdx.x * 256 + threadIdx.x) >> 6;
    int lane = threadIdx.x & 63;
    int n0 = w * 32;
    if (n0 >= N) return;
    int n1 = min(n0 + 32, N);
    int c0 = lane * 2;
    float sc0, sh0, sc1, sh1;
    {
        float m0 = stats[c0] * invN;
        float v0 = fmaxf(stats[128 + c0] * invN - m0 * m0, 0.f);
        sc0 = g[c0] * rsqrtf(v0 + 1e-5f);
        sh0 = be[c0] - m0 * sc0;
        float m1 = stats[c0 + 1] * invN;
        float v1 = fmaxf(stats[128 + c0 + 1] * invN - m1 * m1, 0.f);
        sc1 = g[c0 + 1] * rsqrtf(v1 + 1e-5f);
        sh1 = be[c0 + 1] - m1 * sc1;
    }
    float a0 = 0.f, a1 = 0.f;
    int cur = batch[n0];
    for (int n = n0; n < n1; ++n) {
        int b = batch[n];
        if (b != cur) {
            atomicAdd(&pool[(size_t)cur * 128 + c0], a0);
            atomicAdd(&pool[(size_t)cur * 128 + c0 + 1], a1);
            a0 = a1 = 0.f; cur = b;
        }
        float2 v = *reinterpret_cast<const float2*>(&U[(size_t)n * 128 + c0]);
        a0 += lrelu(fmaf(v.x, sc0, sh0));
        a1 += lrelu(fmaf(v.y, sc1, sh1));
    }
    atomicAdd(&pool[(size_t)cur * 128 + c0], a0);
    atomicAdd(&pool[(size_t)cur * 128 + c0 + 1], a1);
}

// ================================================================ final (BN fused)
__global__ __launch_bounds__(256) void final_kernel_bn(
    const float* __restrict__ U, const float* __restrict__ pool,
    const int* __restrict__ batch,
    const float* __restrict__ stats, const float* __restrict__ g,
    const float* __restrict__ be, float invN,
    const float* __restrict__ wf, const float* __restrict__ bf,
    float* __restrict__ out, int N)
{
    __shared__ float wf_s[512];
    int tid = threadIdx.x;
    for (int i = tid; i < 512; i += 256) wf_s[i] = wf[i];
    __syncthreads();
    int wid = tid >> 6, lane = tid & 63;
    int n = blockIdx.x * 4 + wid;
    if (n >= N) return;
    int cA = lane, cB = 64 + lane;
    float scA, shA, scB, shB;
    {
        float mA = stats[cA] * invN;
        float vA = fmaxf(stats[128 + cA] * invN - mA * mA, 0.f);
        scA = g[cA] * rsqrtf(vA + 1e-5f);
        shA = be[cA] - mA * scA;
        float mB = stats[cB] * invN;
        float vB = fmaxf(stats[128 + cB] * invN - mB * mB, 0.f);
        scB = g[cB] * rsqrtf(vB + 1e-5f);
        shB = be[cB] - mB * scB;
    }
    int b = batch[n];
    float v0 = lrelu(fmaf(U[(size_t)n * 128 + cA], scA, shA));
    float v1 = lrelu(fmaf(U[(size_t)n * 128 + cB], scB, shB));
    float p0 = pool[(size_t)b * 128 + cA];
    float p1 = pool[(size_t)b * 128 + cB];
    float a0 = v0 * wf_s[lane * 2]       + v1 * wf_s[(64 + lane) * 2]
             + p0 * wf_s[(128 + lane) * 2] + p1 * wf_s[(192 + lane) * 2];
    float a1 = v0 * wf_s[lane * 2 + 1]       + v1 * wf_s[(64 + lane) * 2 + 1]
             + p0 * wf_s[(128 + lane) * 2 + 1] + p1 * wf_s[(192 + lane) * 2 + 1];
    #pragma unroll
    for (int off = 32; off >= 1; off >>= 1) {
        a0 += __shfl_down(a0, off);
        a1 += __shfl_down(a1, off);
    }
    if (lane == 0) {
        a0 += bf[0]; a1 += bf[1];
        float mx = fmaxf(a0, a1);
        float e0 = __expf(a0 - mx), e1 = __expf(a1 - mx);
        float inv = 1.f / (e0 + e1);
        out[(size_t)n * 2]     = e0 * inv;
        out[(size_t)n * 2 + 1] = e1 * inv;
    }
}

// ================================================================ launch
extern "C" void kernel_launch(void* const* d_in, const int* in_sizes, int n_in,
                              void* d_out, int out_size, void* d_ws, size_t ws_size,
                              hipStream_t stream)
{
    const float* x0    = (const float*)d_in[0];
    const int*   ei    = (const int*)d_in[1];
    const float* ea    = (const float*)d_in[2];
    const int*   batch = (const int*)d_in[3];
    const int E = in_sizes[1] / 2;
    const int N = in_sizes[3];
    const int* srcv = ei;
    const int* dstv = ei + E;
    const float* wf = (const float*)d_in[37];
    const float* bfp = (const float*)d_in[38];
    float* out = (float*)d_out;
    const float invN = 1.0f / (float)N;
    const int ntiles = (N + 31) / 32;

    // ---- workspace layout (floats) ----
    const size_t base_f = (size_t)2 * N * 128 + (size_t)GNUM * 128 + 6 * 256
                        + (size_t)(N + 1) + (size_t)N + 128 + (size_t)E;
    const size_t full_f = base_f + (size_t)E * 16 + (size_t)E + (size_t)N * 64;
    const bool ro = (ws_size >= full_f * 4);

    float* ws = (float*)d_ws;
    size_t o = 0;
    float* xA    = ws + o; o += (size_t)N * 128;   // U buffer (fp32)
    float* xB    = ws + o; o += (size_t)N * 128;   // hi/lo plane space
    float* eap   = ws + o; o += ro ? (size_t)E * 16 : 0;
    float* bnbf  = ws + o; o += ro ? (size_t)N * 64 : 0;   // bf16 B plane
    float* poolb = ws + o; o += (size_t)GNUM * 128;
    float* statsb= ws + o; o += 6 * 256;
    int* srcp    = (int*)(ws + o); o += ro ? (size_t)E : 0;
    int* off     = (int*)(ws + o); o += (size_t)(N + 1);
    int* cursor  = (int*)(ws + o); o += (size_t)N;
    int* bsumb   = (int*)(ws + o); o += 128;
    int* perm    = (int*)(ws + o);

    // hi/lo bf16 planes live inside xB
    unsigned short* planeh = (unsigned short*)xB;
    unsigned short* bnb = (unsigned short*)bnbf;
    // pre-converted W planes reuse the cursor region (dead after scatter;
    // 86016 shorts = 172 KB <= N*4 = 400 KB)
    unsigned short* wtbuf = (unsigned short*)cursor;

    // ---- CSR build (by destination) ----
    hipMemsetAsync(off, 0, (size_t)(N + 1) * sizeof(int), stream);
    hipMemsetAsync(statsb, 0, (size_t)6 * 256 * sizeof(float), stream);
    hipMemsetAsync(poolb, 0, (size_t)GNUM * 128 * sizeof(float), stream);
    hist_kernel<<<(E + 255) / 256, 256, 0, stream>>>(dstv, off, E);
    const int n1 = N + 1;
    const int nb = (n1 + 1023) / 1024;
    scan_block_kernel<<<nb, 256, 0, stream>>>(off, bsumb, n1);
    scan_carry_kernel<<<1, 128, 0, stream>>>(bsumb, nb);
    scan_add_kernel<<<(n1 + 255) / 256, 256, 0, stream>>>(off, bsumb, cursor, n1, N);
    if (ro)
        scatter_reorder_kernel<<<(E + 255) / 256, 256, 0, stream>>>(
            dstv, srcv, ea, cursor, eap, srcp, E);
    else
        scatter_kernel<<<(E + 255) / 256, 256, 0, stream>>>(dstv, cursor, perm, E);

    // ---- pre-convert W matrices (cursor region is dead now) ----
    wconv_kernel<<<(86016 + 255) / 256, 256, 0, stream>>>(
        (const float*)d_in[4 + 3], (const float*)d_in[4 + 7],
        (const float*)d_in[15 + 3], (const float*)d_in[15 + 7],
        (const float*)d_in[26 + 3], (const float*)d_in[26 + 7], wtbuf);
    const unsigned short* w1p[3] = { wtbuf, wtbuf + 4096 + 16384,
                                     wtbuf + 4096 + 3 * 16384 };
    const unsigned short* w2p[3] = { wtbuf + 4096, wtbuf + 4096 + 2 * 16384,
                                     wtbuf + 4096 + 4 * 16384 };

    const float* g_ea  = ro ? eap  : ea;
    const int*   g_src = ro ? srcp : srcv;
    const int gather_blocks = (N + 3) / 4;

    const float *pg = nullptr, *pbe = nullptr;
    float* pstats = nullptr;

    for (int l = 0; l < 3; l++) {
        int bidx = 4 + l * 11;
        const float* epsp = (const float*)d_in[bidx + 0];
        const float* ew   = (const float*)d_in[bidx + 1];
        const float* eb   = (const float*)d_in[bidx + 2];
        const float* b1   = (const float*)d_in[bidx + 4];
        const float* g1   = (const float*)d_in[bidx + 5];
        const float* be1  = (const float*)d_in[bidx + 6];
        const float* b2   = (const float*)d_in[bidx + 8];
        const float* g2   = (const float*)d_in[bidx + 9];
        const float* be2  = (const float*)d_in[bidx + 10];
        float* st1 = statsb + (size_t)(l * 2) * 256;
        float* st2 = statsb + (size_t)(l * 2 + 1) * 256;

        unsigned short* ah = planeh;                              // hi plane
        unsigned short* al = planeh + (size_t)N * ((l == 0) ? 32 : 128);

        if (l == 0) {
            if (ro) gather_kernel32<true><<<gather_blocks, 256, 0, stream>>>(
                        g_ea, g_src, perm, off, ew, eb, epsp, x0, ah, al, N);
            else    gather_kernel32<false><<<gather_blocks, 256, 0, stream>>>(
                        g_ea, g_src, perm, off, ew, eb, epsp, x0, ah, al, N);
            gemm_copy_mfma_kernel<32><<<GEMM_GRID, 256, 0, stream>>>(
                ah, al, w1p[0], b1, xA, st1, N, ntiles);
        } else {
            if (ro) {
                bnact_kernel<<<(N * 16 + 255) / 256, 256, 0, stream>>>(
                    xA, pstats, pg, pbe, invN, bnb, N);
                gather_kernel128_b<<<gather_blocks, 256, 0, stream>>>(
                    g_ea, g_src, off, ew, eb, epsp, bnb, ah, al, N);
            } else {
                gather_kernel128_bn<<<gather_blocks, 256, 0, stream>>>(
                    g_ea, g_src, perm, off, ew, eb, epsp, xA,
                    pstats, pg, pbe, invN, ah, al, N);
            }
            gemm_copy_mfma_kernel<128><<<GEMM_GRID, 256, 0, stream>>>(
                ah, al, w1p[l], b1, xA, st1, N, ntiles);
        }
        gemm_bn_mfma_kernel<<<GEMM_GRID, 256, 0, stream>>>(
            xA, st1, g1, be1, invN, w2p[l], b2, xA, st2, N, ntiles);
        pstats = st2; pg = g2; pbe = be2;
    }
    pool_kernel_bn<<<((N + 31) / 32 * 64 + 255) / 256, 256, 0, stream>>>(
        xA, batch, pstats, pg, pbe, invN, poolb, N);
    final_kernel_bn<<<(N + 3) / 4, 256, 0, stream>>>(
        xA, poolb, batch, pstats, pg, pbe, invN, wf, bfp, out, N);
}